// Round 7
// baseline (217.659 us; speedup 1.0000x reference)
//
#include <hip/hip_runtime.h>

// out[m,u] = x2[m] + w2[u] - 2 * sum_k x[m,k] * w[k,u]
// x[32768, 128] f32, w[128, 1024] f32, out[32768, 1024] f32
#define M_TOT 32768
#define K_DIM 128
#define U_TOT 1024

#define GBM 64      // rows per pipeline subtile
#define GBN 128     // cols per block
#define NMS 4       // subtiles per block -> block covers 256 rows x 128 cols

typedef short s16x8 __attribute__((ext_vector_type(8)));    // 8 bf16 (4 VGPRs)
typedef float f32x16 __attribute__((ext_vector_type(16)));  // 32x32 MFMA acc

// round-to-nearest-even fp32 -> bf16 (as ushort)
__device__ inline unsigned int f2bf(float f) {
    union { float f; unsigned int u; } v; v.f = f;
    return (v.u + 0x7FFFu + ((v.u >> 16) & 1u)) >> 16;
}

// async global->LDS, 16B per lane; LDS dest = wave-uniform base + lane*16
__device__ inline void async_load16(const void* g, void* l) {
    __builtin_amdgcn_global_load_lds((const __attribute__((address_space(1))) void*)g,
                                     (__attribute__((address_space(3))) void*)l,
                                     16, 0, 0);
}

// prep: x -> bf16 row-major xb + x2 (blocks 0..4095, 8 rows each);
//       w -> w^T bf16 wt + w2 (blocks 4096..4351, 4 u each).  [r3/r4/r5-verified]
__global__ __launch_bounds__(256) void prep_kernel(
    const float* __restrict__ x, const float* __restrict__ w,
    unsigned int* __restrict__ xb, unsigned int* __restrict__ wt,
    float* __restrict__ x2, float* __restrict__ w2)
{
    const int lane = threadIdx.x & 63;
    const int lc = lane & 31;
    if (blockIdx.x < 4096) {
        const int wv = threadIdx.x >> 6;
        const int row = (blockIdx.x << 3) + (wv << 1) + (lane >> 5);
        const float4 v = ((const float4*)(x + (size_t)row * K_DIM))[lc];
        float s = v.x * v.x + v.y * v.y + v.z * v.z + v.w * v.w;
        #pragma unroll
        for (int off = 16; off; off >>= 1) s += __shfl_xor(s, off);
        uint2 pk;
        pk.x = f2bf(v.x) | (f2bf(v.y) << 16);
        pk.y = f2bf(v.z) | (f2bf(v.w) << 16);
        ((uint2*)xb)[(size_t)row * 32 + lc] = pk;   // k = lc*4 .. lc*4+3
        if (lc == 0) x2[row] = s;
    } else {
        const int u = ((blockIdx.x - 4096) << 2) + (threadIdx.x >> 6);
        const float a = w[(size_t)(2 * lane) * U_TOT + u];
        const float b = w[(size_t)(2 * lane + 1) * U_TOT + u];
        float s = a * a + b * b;
        #pragma unroll
        for (int off = 32; off; off >>= 1) s += __shfl_xor(s, off);
        wt[u * 64 + lane] = f2bf(a) | (f2bf(b) << 16);
        if (lane == 0) w2[u] = s;
    }
}

// GEMM v6: A-only LDS pipeline (32 KB) -> 4 blocks/CU, 16 waves/CU.
// B straight global->reg (r4-verified path; wt is 256 KB, L2-resident).
// 1024 blocks x 256 thr (4 waves). Wave (wr=wv>>1, wc2=wv&1): 32 rows x 64
// adjacent cols (two MFMA tiles sharing one A fragment; sector-complete stores).
__global__ __launch_bounds__(256, 4) void gemm_kernel(
    const unsigned short* __restrict__ xb, const unsigned short* __restrict__ wt,
    const float* __restrict__ x2, const float* __restrict__ w2,
    float* __restrict__ out)
{
    __shared__ __align__(16) unsigned short As[2][GBM * K_DIM];   // 2 x 16 KB, swizzled

    const int tid = threadIdx.x;
    const int wv = tid >> 6;
    const int lane = tid & 63;
    const int lc = lane & 31;
    const int hi = lane >> 5;
    const int wr = wv >> 1;                             // 0..1 row group (32 rows)
    const int wc2 = wv & 1;                             // 0..1 col pair (64 cols)

    // XCD mapping: b&7 = XCD; XCD j owns rows [j*4096, (j+1)*4096) in 16 bands
    // of 256 rows; its 8 consecutive u-tile blocks share each band's xb via L2.
    const int b = blockIdx.x;
    const int i = b >> 3;                               // 0..127
    const int ut = i & 7;
    const int band = (b & 7) * 16 + (i >> 3);           // 0..127
    const int u0 = ut * GBN;
    const int mbase = band * (GBM * NMS);               // 256-row band

    // ---- B fragments straight from global (r4-verified layout) ----
    // lane holds B[k][col]: col = wc2*64 (+32) + lc, k = st*16 + hi*8 + 0..7
    const unsigned short* wp0 = wt + ((size_t)(u0 + wc2 * 64 + lc) << 7) + (hi << 3);
    const unsigned short* wp1 = wp0 + (32 << 7);
    s16x8 bfr0[8], bfr1[8];
    #pragma unroll
    for (int st = 0; st < 8; ++st) {
        bfr0[st] = *(const s16x8*)(wp0 + (st << 4));
        bfr1[st] = *(const s16x8*)(wp1 + (st << 4));
    }
    const float w2v0 = w2[u0 + wc2 * 64 + lc];
    const float w2v1 = w2[u0 + wc2 * 64 + 32 + lc];

    // ---- prologue: A[0] DMA (linear LDS dest + inverse-swizzled source) ----
    #pragma unroll
    for (int i2 = 0; i2 < 4; ++i2) {
        const int p = i2 * 256 + tid;                   // physical 16B slot
        const int row = p >> 4;
        const int j = (p & 15) ^ (row & 15);
        async_load16(xb + ((size_t)(mbase + row) << 7) + j * 8,
                     &As[0][(i2 * 256 + (tid & 192)) * 8]);
    }
    __syncthreads();                                    // A[0] resident

    #pragma unroll
    for (int ms = 0; ms < NMS; ++ms) {
        // issue next A-tile DMA first: flies under this subtile's compute+stores
        if (ms + 1 < NMS) {
            #pragma unroll
            for (int i2 = 0; i2 < 4; ++i2) {
                const int p = i2 * 256 + tid;
                const int row = p >> 4;
                const int j = (p & 15) ^ (row & 15);
                async_load16(xb + ((size_t)(mbase + (ms + 1) * GBM + row) << 7) + j * 8,
                             &As[(ms + 1) & 1][(i2 * 256 + (tid & 192)) * 8]);
            }
        }

        const int mb = mbase + ms * GBM + wr * 32;
        const float x2row = x2[mb + lc];                // 128B broadcast load

        f32x16 acc0 = {}, acc1 = {};
        #pragma unroll
        for (int st = 0; st < 8; ++st) {
            const int row = wr * 32 + lc;
            const int j0 = (st << 1) + hi;
            const s16x8 af = *(const s16x8*)&As[ms & 1][((row << 4) + (j0 ^ (row & 15))) * 8];
            acc0 = __builtin_amdgcn_mfma_f32_32x32x16_bf16(af, bfr0[st], acc0, 0, 0, 0);
            acc1 = __builtin_amdgcn_mfma_f32_32x32x16_bf16(af, bfr1[st], acc1, 0, 0, 0);
        }

        // C/D 32x32: col=lane&31, row=(r&3)+8*(r>>2)+4*hi (m74/m101-verified;
        // epilogue identical to r3/r5-passed kernels). Two 128B stores per row
        // back-to-back from the same wave -> 256B sectors complete immediately.
        float* op = out + (size_t)mb * U_TOT + u0 + wc2 * 64 + lc;
        #pragma unroll
        for (int r = 0; r < 16; ++r) {
            const int t = (r & 3) + ((r >> 2) << 3);
            const int tt = t + (hi << 2);
            const float xs = __shfl(x2row, tt + (lane & 32));
            op[(size_t)tt * U_TOT]      = xs + w2v0 - 2.0f * acc0[r];   // cols +0..31
            op[(size_t)tt * U_TOT + 32] = xs + w2v1 - 2.0f * acc1[r];   // cols +32..63
        }
        if (ms + 1 < NMS) __syncthreads();              // one drain+barrier per subtile
    }
}

// Fallback (no workspace): correct fp32 path, used only if ws_size is too small.
__global__ __launch_bounds__(256) void fallback_kernel(
    const float* __restrict__ x, const float* __restrict__ w,
    float* __restrict__ out)
{
    __shared__ float xrow[K_DIM];
    const int m = blockIdx.x;
    const int tid = threadIdx.x;
    if (tid < K_DIM) xrow[tid] = x[(size_t)m * K_DIM + tid];
    __syncthreads();
    float x2 = 0.f;
    #pragma unroll
    for (int k = 0; k < K_DIM; ++k) x2 += xrow[k] * xrow[k];
    #pragma unroll
    for (int uu = 0; uu < 4; ++uu) {
        const int u = uu * 256 + tid;
        float dot = 0.f, w2 = 0.f;
        for (int k = 0; k < K_DIM; ++k) {
            const float wv = w[(size_t)k * U_TOT + u];
            dot += xrow[k] * wv;
            w2 += wv * wv;
        }
        out[(size_t)m * U_TOT + u] = x2 + w2 - 2.0f * dot;
    }
}

extern "C" void kernel_launch(void* const* d_in, const int* in_sizes, int n_in,
                              void* d_out, int out_size, void* d_ws, size_t ws_size,
                              hipStream_t stream) {
    const float* x = (const float*)d_in[0];
    const float* w = (const float*)d_in[1];
    float* out = (float*)d_out;

    // ws layout: xb bf16[32768*128] | wt bf16[1024*128] | x2 f32[32768] | w2 f32[1024]
    const size_t need = (size_t)M_TOT * K_DIM * 2 + (size_t)U_TOT * K_DIM * 2
                      + (size_t)M_TOT * 4 + (size_t)U_TOT * 4;
    if (ws_size < need) {
        fallback_kernel<<<M_TOT, 256, 0, stream>>>(x, w, out);
        return;
    }

    unsigned short* xb = (unsigned short*)d_ws;
    unsigned short* wt = xb + (size_t)M_TOT * K_DIM;
    float* x2 = (float*)(wt + (size_t)U_TOT * K_DIM);
    float* w2 = x2 + M_TOT;

    prep_kernel<<<4096 + 256, 256, 0, stream>>>(x, w, (unsigned int*)xb,
                                                (unsigned int*)wt, x2, w2);
    gemm_kernel<<<(M_TOT / (GBM * NMS)) * (U_TOT / GBN), 256, 0, stream>>>(xb, wt, x2, w2, out);
}

// Round 9
// 155.787 us; speedup vs baseline: 1.3972x; 1.3972x over previous
//
#include <hip/hip_runtime.h>

// out[m,u] = x2[m] + w2[u] - 2 * sum_k x[m,k] * w[k,u]
// x[32768, 128] f32, w[128, 1024] f32, out[32768, 1024] f32
#define M_TOT 32768
#define K_DIM 128
#define U_TOT 1024

#define BMR 64      // rows per block (read ONCE grid-wide)
#define UCH 128     // u-cols per chunk
#define NCH 8       // chunks per block -> block covers 64 rows x 1024 cols

typedef short s16x8 __attribute__((ext_vector_type(8)));    // 8 bf16 (4 VGPRs)
typedef float f32x16 __attribute__((ext_vector_type(16)));  // 32x32 MFMA acc

// round-to-nearest-even fp32 -> bf16 (as ushort)
__device__ inline unsigned int f2bf(float f) {
    union { float f; unsigned int u; } v; v.f = f;
    return (v.u + 0x7FFFu + ((v.u >> 16) & 1u)) >> 16;
}

// async global->LDS, 16B per lane; LDS dest = wave-uniform base + lane*16
__device__ inline void async_load16(const void* g, void* l) {
    __builtin_amdgcn_global_load_lds((const __attribute__((address_space(1))) void*)g,
                                     (__attribute__((address_space(3))) void*)l,
                                     16, 0, 0);
}

// prep: x -> bf16 row-major xb + x2 (blocks 0..4095, 8 rows each);
//       w -> w^T bf16 wt + w2 (blocks 4096..4351, 4 u each).  [r3/r5/r7-verified]
__global__ __launch_bounds__(256) void prep_kernel(
    const float* __restrict__ x, const float* __restrict__ w,
    unsigned int* __restrict__ xb, unsigned int* __restrict__ wt,
    float* __restrict__ x2, float* __restrict__ w2)
{
    const int lane = threadIdx.x & 63;
    const int lc = lane & 31;
    if (blockIdx.x < 4096) {
        const int wv = threadIdx.x >> 6;
        const int row = (blockIdx.x << 3) + (wv << 1) + (lane >> 5);
        const float4 v = ((const float4*)(x + (size_t)row * K_DIM))[lc];
        float s = v.x * v.x + v.y * v.y + v.z * v.z + v.w * v.w;
        #pragma unroll
        for (int off = 16; off; off >>= 1) s += __shfl_xor(s, off);
        uint2 pk;
        pk.x = f2bf(v.x) | (f2bf(v.y) << 16);
        pk.y = f2bf(v.z) | (f2bf(v.w) << 16);
        ((uint2*)xb)[(size_t)row * 32 + lc] = pk;   // k = lc*4 .. lc*4+3
        if (lc == 0) x2[row] = s;
    } else {
        const int u = ((blockIdx.x - 4096) << 2) + (threadIdx.x >> 6);
        const float a = w[(size_t)(2 * lane) * U_TOT + u];
        const float b = w[(size_t)(2 * lane + 1) * U_TOT + u];
        float s = a * a + b * b;
        #pragma unroll
        for (int off = 32; off; off >>= 1) s += __shfl_xor(s, off);
        wt[u * 64 + lane] = f2bf(a) | (f2bf(b) << 16);
        if (lane == 0) w2[u] = s;
    }
}

// GEMM v8: block = 64 rows x ALL 1024 cols. xb read ONCE grid-wide (8 MB total).
// A (16 KB) staged once in LDS; B streamed in 128-col chunks, double-buffered
// (2x32 KB), r3/r5 barrier cadence. Epilogue recombines acc halves into
// whole-row registers via __shfl_xor(.,32) + lane-select (bulletproof
// semantics; replaces r8's wrong permlane direction) -> every store = 64
// lanes x 4B = one contiguous 256B sector in ONE instruction.
// 512 blocks x 256 thr (4 waves), 80 KB LDS -> 2 blocks/CU.
__global__ __launch_bounds__(256, 2) void gemm_kernel(
    const unsigned short* __restrict__ xb, const unsigned short* __restrict__ wt,
    const float* __restrict__ x2, const float* __restrict__ w2,
    float* __restrict__ out)
{
    __shared__ __align__(16) unsigned short As[BMR * K_DIM];      // 16 KB, swizzled
    __shared__ __align__(16) unsigned short Bs[2][UCH * K_DIM];   // 2 x 32 KB, swizzled

    const int tid = threadIdx.x;
    const int wv = tid >> 6;
    const int lane = tid & 63;
    const int lc = lane & 31;
    const int hi = lane >> 5;
    const int wr = wv >> 1;                             // 0..1 row group (32 rows)
    const int wc2 = wv & 1;                             // 0..1 col pair (64 cols of chunk)

    const int b = blockIdx.x;                           // 0..511
    const int mbase = b * BMR;                          // rows b*64..+63, read once

    // ---- prologue: A (16 KB, once) + B chunk 0 (32 KB) ----
    #pragma unroll
    for (int i2 = 0; i2 < 4; ++i2) {                    // A
        const int p = i2 * 256 + tid;                   // physical 16B slot
        const int row = p >> 4;
        const int j = (p & 15) ^ (row & 15);
        async_load16(xb + ((size_t)(mbase + row) << 7) + j * 8,
                     &As[(i2 * 256 + (tid & 192)) * 8]);
    }
    #pragma unroll
    for (int i2 = 0; i2 < 8; ++i2) {                    // B[0]: cols 0..127
        const int p = i2 * 256 + tid;
        const int row = p >> 4;
        const int j = (p & 15) ^ (row & 15);
        async_load16(wt + ((size_t)row << 7) + j * 8,
                     &Bs[0][(i2 * 256 + (tid & 192)) * 8]);
    }

    const float x2row = x2[mbase + wr * 32 + lc];       // wave's 32 rows, once
    __syncthreads();                                    // A + B[0] resident

    #pragma unroll
    for (int ut = 0; ut < NCH; ++ut) {
        const int u0 = ut * UCH;
        // issue next B-chunk DMA first: flies under this chunk's compute+stores
        if (ut + 1 < NCH) {
            #pragma unroll
            for (int i2 = 0; i2 < 8; ++i2) {
                const int p = i2 * 256 + tid;
                const int row = p >> 4;
                const int j = (p & 15) ^ (row & 15);
                async_load16(wt + ((size_t)(u0 + UCH + row) << 7) + j * 8,
                             &Bs[(ut + 1) & 1][(i2 * 256 + (tid & 192)) * 8]);
            }
        }

        // ---- B fragments from LDS (r5/r6-verified layout) ----
        s16x8 bfr0[8], bfr1[8];
        #pragma unroll
        for (int st = 0; st < 8; ++st) {
            const int j0 = (st << 1) + hi;
            const int r0 = wc2 * 64 + lc;
            const int r1 = wc2 * 64 + 32 + lc;
            bfr0[st] = *(const s16x8*)&Bs[ut & 1][((r0 << 4) + (j0 ^ (r0 & 15))) * 8];
            bfr1[st] = *(const s16x8*)&Bs[ut & 1][((r1 << 4) + (j0 ^ (r1 & 15))) * 8];
        }

        f32x16 acc0 = {}, acc1 = {};
        #pragma unroll
        for (int st = 0; st < 8; ++st) {
            const int row = wr * 32 + lc;
            const int j0 = (st << 1) + hi;
            const s16x8 af = *(const s16x8*)&As[((row << 4) + (j0 ^ (row & 15))) * 8];
            acc0 = __builtin_amdgcn_mfma_f32_32x32x16_bf16(af, bfr0[st], acc0, 0, 0, 0);
            acc1 = __builtin_amdgcn_mfma_f32_32x32x16_bf16(af, bfr1[st], acc1, 0, 0, 0);
        }

        // ---- Epilogue: whole-row recombination with defined semantics.
        // C/D 32x32: col=lane&31, row=(r&3)+8*(r>>2)+4*hi (m74/m101-verified).
        //   row t  : lane<32 -> acc0(lane)      ; lane>=32 -> acc1 from lane-32
        //   row t+4: lane<32 -> acc0 from lane+32; lane>=32 -> acc1(lane)
        // __shfl_xor(v,32) swaps halves -> each store = 256B contiguous sector.
        const float w2l = w2[u0 + wc2 * 64 + lane];     // per-lane output col
        float* op = out + (size_t)(mbase + wr * 32) * U_TOT + u0 + wc2 * 64 + lane;
        #pragma unroll
        for (int r = 0; r < 16; ++r) {
            const int t = (r & 3) + ((r >> 2) << 3);
            const float sw1 = __shfl_xor(acc1[r], 32);  // lane>=32: acc1.lo half
            const float sw0 = __shfl_xor(acc0[r], 32);  // lane<32 : acc0.hi half
            const float dt  = (lane < 32) ? acc0[r] : sw1;   // row t,   col=lane
            const float dt4 = (lane < 32) ? sw0 : acc1[r];   // row t+4, col=lane
            const float xs0 = __shfl(x2row, t);
            const float xs1 = __shfl(x2row, t + 4);
            op[(size_t)t * U_TOT]       = xs0 + w2l - 2.0f * dt;
            op[(size_t)(t + 4) * U_TOT] = xs1 + w2l - 2.0f * dt4;
        }
        if (ut + 1 < NCH) __syncthreads();              // one drain+barrier per chunk
    }
}

// Fallback (no workspace): correct fp32 path, used only if ws_size is too small.
__global__ __launch_bounds__(256) void fallback_kernel(
    const float* __restrict__ x, const float* __restrict__ w,
    float* __restrict__ out)
{
    __shared__ float xrow[K_DIM];
    const int m = blockIdx.x;
    const int tid = threadIdx.x;
    if (tid < K_DIM) xrow[tid] = x[(size_t)m * K_DIM + tid];
    __syncthreads();
    float x2 = 0.f;
    #pragma unroll
    for (int k = 0; k < K_DIM; ++k) x2 += xrow[k] * xrow[k];
    #pragma unroll
    for (int uu = 0; uu < 4; ++uu) {
        const int u = uu * 256 + tid;
        float dot = 0.f, w2 = 0.f;
        for (int k = 0; k < K_DIM; ++k) {
            const float wv = w[(size_t)k * U_TOT + u];
            dot += xrow[k] * wv;
            w2 += wv * wv;
        }
        out[(size_t)m * U_TOT + u] = x2 + w2 - 2.0f * dot;
    }
}

extern "C" void kernel_launch(void* const* d_in, const int* in_sizes, int n_in,
                              void* d_out, int out_size, void* d_ws, size_t ws_size,
                              hipStream_t stream) {
    const float* x = (const float*)d_in[0];
    const float* w = (const float*)d_in[1];
    float* out = (float*)d_out;

    // ws layout: xb bf16[32768*128] | wt bf16[1024*128] | x2 f32[32768] | w2 f32[1024]
    const size_t need = (size_t)M_TOT * K_DIM * 2 + (size_t)U_TOT * K_DIM * 2
                      + (size_t)M_TOT * 4 + (size_t)U_TOT * 4;
    if (ws_size < need) {
        fallback_kernel<<<M_TOT, 256, 0, stream>>>(x, w, out);
        return;
    }

    unsigned short* xb = (unsigned short*)d_ws;
    unsigned short* wt = xb + (size_t)M_TOT * K_DIM;
    float* x2 = (float*)(wt + (size_t)U_TOT * K_DIM);
    float* w2 = x2 + M_TOT;

    prep_kernel<<<4096 + 256, 256, 0, stream>>>(x, w, (unsigned int*)xb,
                                                (unsigned int*)wt, x2, w2);
    gemm_kernel<<<M_TOT / BMR, 256, 0, stream>>>(xb, wt, x2, w2, out);
}

// Round 11
// 153.697 us; speedup vs baseline: 1.4162x; 1.0136x over previous
//
#include <hip/hip_runtime.h>

// out[m,u] = x2[m] + w2[u] - 2 * sum_k x[m,k] * w[k,u]
// x[32768, 128] f32, w[128, 1024] f32, out[32768, 1024] f32
#define M_TOT 32768
#define K_DIM 128
#define U_TOT 1024

#define BMR 64      // rows per block (read ONCE grid-wide)
#define UCH 128     // u-cols per chunk
#define NCH 8       // chunks per block -> block covers 64 rows x 1024 cols

typedef short s16x8 __attribute__((ext_vector_type(8)));    // 8 bf16 (4 VGPRs)
typedef float f32x16 __attribute__((ext_vector_type(16)));  // 32x32 MFMA acc

// round-to-nearest-even fp32 -> bf16 (as ushort)
__device__ inline unsigned int f2bf(float f) {
    union { float f; unsigned int u; } v; v.f = f;
    return (v.u + 0x7FFFu + ((v.u >> 16) & 1u)) >> 16;
}

// async global->LDS, 16B per lane; LDS dest = wave-uniform base + lane*16
__device__ inline void async_load16(const void* g, void* l) {
    __builtin_amdgcn_global_load_lds((const __attribute__((address_space(1))) void*)g,
                                     (__attribute__((address_space(3))) void*)l,
                                     16, 0, 0);
}

// prep: x -> bf16 row-major xb + x2 (blocks 0..4095, 8 rows each);
//       w -> w^T bf16 wt + w2 (blocks 4096..4351, 4 u each).  [r3..r9-verified]
__global__ __launch_bounds__(256) void prep_kernel(
    const float* __restrict__ x, const float* __restrict__ w,
    unsigned int* __restrict__ xb, unsigned int* __restrict__ wt,
    float* __restrict__ x2, float* __restrict__ w2)
{
    const int lane = threadIdx.x & 63;
    const int lc = lane & 31;
    if (blockIdx.x < 4096) {
        const int wv = threadIdx.x >> 6;
        const int row = (blockIdx.x << 3) + (wv << 1) + (lane >> 5);
        const float4 v = ((const float4*)(x + (size_t)row * K_DIM))[lc];
        float s = v.x * v.x + v.y * v.y + v.z * v.z + v.w * v.w;
        #pragma unroll
        for (int off = 16; off; off >>= 1) s += __shfl_xor(s, off);
        uint2 pk;
        pk.x = f2bf(v.x) | (f2bf(v.y) << 16);
        pk.y = f2bf(v.z) | (f2bf(v.w) << 16);
        ((uint2*)xb)[(size_t)row * 32 + lc] = pk;   // k = lc*4 .. lc*4+3
        if (lc == 0) x2[row] = s;
    } else {
        const int u = ((blockIdx.x - 4096) << 2) + (threadIdx.x >> 6);
        const float a = w[(size_t)(2 * lane) * U_TOT + u];
        const float b = w[(size_t)(2 * lane + 1) * U_TOT + u];
        float s = a * a + b * b;
        #pragma unroll
        for (int off = 32; off; off >>= 1) s += __shfl_xor(s, off);
        wt[u * 64 + lane] = f2bf(a) | (f2bf(b) << 16);
        if (lane == 0) w2[u] = s;
    }
}

// GEMM v9 = v8 (passed, absmax 2.0) with ONE change: counted-vmcnt barriers
// (catalog T4) instead of full-drain __syncthreads in the chunk loop.
// Per chunk, issue order is [8 prefetch loads][<=1 w2 load][32 stores]
// (pinned by sched_barrier after the prefetch block). vmcnt retires IN ORDER,
// so "s_waitcnt vmcnt(24)" guarantees the prefetch loads (oldest) retired --
// LDS buffer swap safe -- while the newest stores keep flying across the
// barrier. Stores overlap the next chunk's compute instead of draining 8x.
__global__ __launch_bounds__(256, 2) void gemm_kernel(
    const unsigned short* __restrict__ xb, const unsigned short* __restrict__ wt,
    const float* __restrict__ x2, const float* __restrict__ w2,
    float* __restrict__ out)
{
    __shared__ __align__(16) unsigned short As[BMR * K_DIM];      // 16 KB, swizzled
    __shared__ __align__(16) unsigned short Bs[2][UCH * K_DIM];   // 2 x 32 KB, swizzled

    const int tid = threadIdx.x;
    const int wv = tid >> 6;
    const int lane = tid & 63;
    const int lc = lane & 31;
    const int hi = lane >> 5;
    const int wr = wv >> 1;                             // 0..1 row group (32 rows)
    const int wc2 = wv & 1;                             // 0..1 col pair (64 cols of chunk)

    const int b = blockIdx.x;                           // 0..511
    const int mbase = b * BMR;                          // rows b*64..+63, read once

    // ---- prologue: A (16 KB, once) + B chunk 0 (32 KB) ----
    #pragma unroll
    for (int i2 = 0; i2 < 4; ++i2) {                    // A
        const int p = i2 * 256 + tid;                   // physical 16B slot
        const int row = p >> 4;
        const int j = (p & 15) ^ (row & 15);
        async_load16(xb + ((size_t)(mbase + row) << 7) + j * 8,
                     &As[(i2 * 256 + (tid & 192)) * 8]);
    }
    #pragma unroll
    for (int i2 = 0; i2 < 8; ++i2) {                    // B[0]: cols 0..127
        const int p = i2 * 256 + tid;
        const int row = p >> 4;
        const int j = (p & 15) ^ (row & 15);
        async_load16(wt + ((size_t)row << 7) + j * 8,
                     &Bs[0][(i2 * 256 + (tid & 192)) * 8]);
    }

    const float x2row = x2[mbase + wr * 32 + lc];       // wave's 32 rows, once
    __syncthreads();                                    // prologue: full drain ok

    #pragma unroll
    for (int ut = 0; ut < NCH; ++ut) {
        const int u0 = ut * UCH;
        // issue next B-chunk DMA first: flies under this chunk's compute+stores
        if (ut + 1 < NCH) {
            #pragma unroll
            for (int i2 = 0; i2 < 8; ++i2) {
                const int p = i2 * 256 + tid;
                const int row = p >> 4;
                const int j = (p & 15) ^ (row & 15);
                async_load16(wt + ((size_t)(u0 + UCH + row) << 7) + j * 8,
                             &Bs[(ut + 1) & 1][(i2 * 256 + (tid & 192)) * 8]);
            }
            // pin: prefetch loads are issued BEFORE everything below (the
            // in-order vmcnt count at the barrier depends on this).
            __builtin_amdgcn_sched_barrier(0);
        }

        // ---- B fragments from LDS (r5/r9-verified layout) ----
        s16x8 bfr0[8], bfr1[8];
        #pragma unroll
        for (int st = 0; st < 8; ++st) {
            const int j0 = (st << 1) + hi;
            const int r0 = wc2 * 64 + lc;
            const int r1 = wc2 * 64 + 32 + lc;
            bfr0[st] = *(const s16x8*)&Bs[ut & 1][((r0 << 4) + (j0 ^ (r0 & 15))) * 8];
            bfr1[st] = *(const s16x8*)&Bs[ut & 1][((r1 << 4) + (j0 ^ (r1 & 15))) * 8];
        }

        f32x16 acc0 = {}, acc1 = {};
        #pragma unroll
        for (int st = 0; st < 8; ++st) {
            const int row = wr * 32 + lc;
            const int j0 = (st << 1) + hi;
            const s16x8 af = *(const s16x8*)&As[((row << 4) + (j0 ^ (row & 15))) * 8];
            acc0 = __builtin_amdgcn_mfma_f32_32x32x16_bf16(af, bfr0[st], acc0, 0, 0, 0);
            acc1 = __builtin_amdgcn_mfma_f32_32x32x16_bf16(af, bfr1[st], acc1, 0, 0, 0);
        }

        // ---- Epilogue (r9-verified): whole-row recombination, 256B sector
        // stores. C/D 32x32: col=lane&31, row=(r&3)+8*(r>>2)+4*hi.
        const float w2l = w2[u0 + wc2 * 64 + lane];     // per-lane output col
        float* op = out + (size_t)(mbase + wr * 32) * U_TOT + u0 + wc2 * 64 + lane;
        #pragma unroll
        for (int r = 0; r < 16; ++r) {
            const int t = (r & 3) + ((r >> 2) << 3);
            const float sw1 = __shfl_xor(acc1[r], 32);  // lane>=32: acc1.lo half
            const float sw0 = __shfl_xor(acc0[r], 32);  // lane<32 : acc0.hi half
            const float dt  = (lane < 32) ? acc0[r] : sw1;   // row t,   col=lane
            const float dt4 = (lane < 32) ? sw0 : acc1[r];   // row t+4, col=lane
            const float xs0 = __shfl(x2row, t);
            const float xs1 = __shfl(x2row, t + 4);
            op[(size_t)t * U_TOT]       = xs0 + w2l - 2.0f * dt;
            op[(size_t)(t + 4) * U_TOT] = xs1 + w2l - 2.0f * dt4;
        }

        if (ut + 1 < NCH) {
            // T4 counted barrier: retire everything except the newest <=24
            // vmem ops (this chunk's stores). In-order retirement => the 8
            // prefetch loads (older than the stores) are complete; the 24
            // margin absorbs any stray vmem op the scheduler interleaves.
            asm volatile("s_waitcnt vmcnt(24)" ::: "memory");
            __builtin_amdgcn_s_barrier();
            __builtin_amdgcn_sched_barrier(0);
        }
    }
}

// Fallback (no workspace): correct fp32 path, used only if ws_size is too small.
__global__ __launch_bounds__(256) void fallback_kernel(
    const float* __restrict__ x, const float* __restrict__ w,
    float* __restrict__ out)
{
    __shared__ float xrow[K_DIM];
    const int m = blockIdx.x;
    const int tid = threadIdx.x;
    if (tid < K_DIM) xrow[tid] = x[(size_t)m * K_DIM + tid];
    __syncthreads();
    float x2 = 0.f;
    #pragma unroll
    for (int k = 0; k < K_DIM; ++k) x2 += xrow[k] * xrow[k];
    #pragma unroll
    for (int uu = 0; uu < 4; ++uu) {
        const int u = uu * 256 + tid;
        float dot = 0.f, w2 = 0.f;
        for (int k = 0; k < K_DIM; ++k) {
            const float wv = w[(size_t)k * U_TOT + u];
            dot += xrow[k] * wv;
            w2 += wv * wv;
        }
        out[(size_t)m * U_TOT + u] = x2 + w2 - 2.0f * dot;
    }
}

extern "C" void kernel_launch(void* const* d_in, const int* in_sizes, int n_in,
                              void* d_out, int out_size, void* d_ws, size_t ws_size,
                              hipStream_t stream) {
    const float* x = (const float*)d_in[0];
    const float* w = (const float*)d_in[1];
    float* out = (float*)d_out;

    // ws layout: xb bf16[32768*128] | wt bf16[1024*128] | x2 f32[32768] | w2 f32[1024]
    const size_t need = (size_t)M_TOT * K_DIM * 2 + (size_t)U_TOT * K_DIM * 2
                      + (size_t)M_TOT * 4 + (size_t)U_TOT * 4;
    if (ws_size < need) {
        fallback_kernel<<<M_TOT, 256, 0, stream>>>(x, w, out);
        return;
    }

    unsigned short* xb = (unsigned short*)d_ws;
    unsigned short* wt = xb + (size_t)M_TOT * K_DIM;
    float* x2 = (float*)(wt + (size_t)U_TOT * K_DIM);
    float* w2 = x2 + M_TOT;

    prep_kernel<<<4096 + 256, 256, 0, stream>>>(x, w, (unsigned int*)xb,
                                                (unsigned int*)wt, x2, w2);
    gemm_kernel<<<M_TOT / BMR, 256, 0, stream>>>(xb, wt, x2, w2, out);
}